// Round 1
// baseline (655.473 us; speedup 1.0000x reference)
//
#include <hip/hip_runtime.h>

#define BB 4
#define CIN 256
#define COUT 256
#define HH 64
#define WW 64
#define KK 9
#define OC2 18   // 2*K offset channels

// ---------------------------------------------------------------------------
// Kernel 1: transpose dcn_w [co][c][k] -> Wt[(c*9+k)][co]  (coalesced writes)
// ---------------------------------------------------------------------------
__global__ __launch_bounds__(256) void wt_transpose_kernel(
    const float* __restrict__ w, float* __restrict__ wt)
{
    int idx = blockIdx.x * 256 + threadIdx.x;   // idx = ck*256 + co
    if (idx < COUT * CIN * KK) {
        int co = idx & (COUT - 1);
        int ck = idx >> 8;
        wt[idx] = w[co * (CIN * KK) + ck];
    }
}

// ---------------------------------------------------------------------------
// Kernel 2: offset conv (fp32, 3x3, pad 1): x[b,256,64,64] -> offs[b,18,64,64]
// grid = B * 64 tiles (8x8 px), block = 256 (4 waves; wave w owns an oc slice)
// ---------------------------------------------------------------------------
__global__ __launch_bounds__(256) void offset_conv_kernel(
    const float* __restrict__ x, const float* __restrict__ ow,
    const float* __restrict__ ob, float* __restrict__ offs)
{
    const int blk  = blockIdx.x;
    const int b    = blk >> 6;
    const int tile = blk & 63;
    const int ty0  = (tile >> 3) * 8;
    const int tx0  = (tile & 7) * 8;
    const int t    = threadIdx.x;
    const int px   = t & 63;
    const int wv   = t >> 6;      // wave id 0..3
    const int py   = px >> 3;
    const int pxx  = px & 7;

    // oc split: 5,5,5,3 across waves (wave-uniform; force scalar addressing)
    int oc_start = (wv < 3) ? wv * 5 : 15;
    int oc_cnt   = (wv < 3) ? 5 : 3;
    oc_start = __builtin_amdgcn_readfirstlane(oc_start);
    oc_cnt   = __builtin_amdgcn_readfirstlane(oc_cnt);

    __shared__ float xt[32][10][10];
    float acc[5] = {0.f, 0.f, 0.f, 0.f, 0.f};

    const float* xb = x + (size_t)b * (CIN * HH * WW);

    for (int c0 = 0; c0 < CIN; c0 += 32) {
        for (int idx = t; idx < 3200; idx += 256) {
            int cc  = idx / 100;
            int rem = idx - cc * 100;
            int r   = rem / 10;
            int cl  = rem - r * 10;
            int gy = ty0 - 1 + r, gx = tx0 - 1 + cl;
            float v = 0.f;
            if (gy >= 0 && gy < HH && gx >= 0 && gx < WW)
                v = xb[(c0 + cc) * (HH * WW) + gy * WW + gx];
            xt[cc][r][cl] = v;
        }
        __syncthreads();

        for (int cc = 0; cc < 32; ++cc) {
            float xv[9];
#pragma unroll
            for (int j = 0; j < 9; ++j) {
                int ky = j / 3, kx = j - ky * 3;
                xv[j] = xt[cc][py + ky][pxx + kx];
            }
#pragma unroll 5
            for (int oi = 0; oi < 5; ++oi) {
                if (oi < oc_cnt) {
                    const float* wrow = ow + (oc_start + oi) * (CIN * KK) + (c0 + cc) * KK;
                    float s = acc[oi];
#pragma unroll
                    for (int j = 0; j < 9; ++j) s += xv[j] * wrow[j];
                    acc[oi] = s;
                }
            }
        }
        __syncthreads();
    }

    const int gy = ty0 + py, gx = tx0 + pxx;
    for (int oi = 0; oi < oc_cnt; ++oi) {
        int oc = oc_start + oi;
        offs[((b * OC2 + oc) * HH + gy) * WW + gx] = acc[oi] + ob[oc];
    }
}

// ---------------------------------------------------------------------------
// Kernel 3: deformable gather + main conv as implicit GEMM.
// grid = 512 blocks: each block = 32 consecutive pixels (one half-row) x 256 couts.
// K-loop over 256 channels in chunks of 8; A-tile [8c][9k][32px] gathered to LDS.
// Thread t accumulates acc[4px][8co].
// ---------------------------------------------------------------------------
__global__ __launch_bounds__(256) void dcn_main_kernel(
    const float* __restrict__ x, const float* __restrict__ offs,
    const float* __restrict__ wt, const float* __restrict__ bias,
    float* __restrict__ out)
{
    const int blk = blockIdx.x;           // 512
    const int b   = blk >> 7;             // 128 tiles per image
    const int p0  = (blk & 127) * 32;     // first pixel of tile
    const int y   = p0 >> 6;              // row
    const int x0  = p0 & 63;              // 0 or 32

    const int t = threadIdx.x;

    __shared__ __align__(16) float A[8][9][32];     // 9.2 KB
    __shared__ __align__(16) float cw[9][32][4];    // 4.6 KB bilinear weights
    __shared__ __align__(16) int4  ci[9][32];       // 4.6 KB clamped corners (y0,y1,x0,x1)

    // ---- per-(px,k) sampling coords ----
    for (int idx = t; idx < 288; idx += 256) {
        int k  = idx >> 5;      // 0..8
        int pp = idx & 31;
        int gx = x0 + pp;
        int ky = k / 3, kx = k - ky * 3;
        float dy = offs[((b * OC2 + 2 * k    ) * HH + y) * WW + gx];
        float dx = offs[((b * OC2 + 2 * k + 1) * HH + y) * WW + gx];
        float sy = (float)(y - 1 + ky) + dy;
        float sx = (float)(gx - 1 + kx) + dx;
        float fy = floorf(sy), fx = floorf(sx);
        int   y0i = (int)fy,   x0i = (int)fx;
        float wy1 = sy - fy,   wx1 = sx - fx;
        float wy0 = 1.f - wy1, wx0 = 1.f - wx1;
        bool vy0 = (y0i >= 0)     && (y0i < HH);
        bool vy1 = (y0i + 1 >= 0) && (y0i + 1 < HH);
        bool vx0 = (x0i >= 0)     && (x0i < WW);
        bool vx1 = (x0i + 1 >= 0) && (x0i + 1 < WW);
        cw[k][pp][0] = (vy0 && vx0) ? wy0 * wx0 : 0.f;
        cw[k][pp][1] = (vy0 && vx1) ? wy0 * wx1 : 0.f;
        cw[k][pp][2] = (vy1 && vx0) ? wy1 * wx0 : 0.f;
        cw[k][pp][3] = (vy1 && vx1) ? wy1 * wx1 : 0.f;
        int y0c = min(max(y0i, 0), HH - 1);
        int y1c = min(max(y0i + 1, 0), HH - 1);
        int x0c = min(max(x0i, 0), WW - 1);
        int x1c = min(max(x0i + 1, 0), WW - 1);
        ci[k][pp] = make_int4(y0c, y1c, x0c, x1c);
    }
    __syncthreads();

    float acc[4][8];
#pragma unroll
    for (int i = 0; i < 4; ++i)
#pragma unroll
        for (int j = 0; j < 8; ++j) acc[i][j] = 0.f;

    const int mypx = t & 31;        // staging: pixel
    const int mycc = t >> 5;        // staging: channel within chunk (0..7)
    const int px0  = (t & 7) * 4;   // compute: first of 4 pixels
    const int co0  = (t >> 3) * 8;  // compute: first of 8 couts

    for (int c0 = 0; c0 < CIN; c0 += 8) {
        // ---- stage A-tile via bilinear gather ----
        const float* xp = x + ((size_t)b * CIN + c0 + mycc) * (HH * WW);
#pragma unroll
        for (int k = 0; k < 9; ++k) {
            float4 w4 = *(const float4*)&cw[k][mypx][0];
            int4   c4 = ci[k][mypx];
            float v = w4.x * xp[c4.x * WW + c4.z]
                    + w4.y * xp[c4.x * WW + c4.w]
                    + w4.z * xp[c4.y * WW + c4.z]
                    + w4.w * xp[c4.y * WW + c4.w];
            A[mycc][k][mypx] = v;
        }
        __syncthreads();

        // ---- GEMM micro-tile: 4px x 8co per thread ----
        for (int cc = 0; cc < 8; ++cc) {
#pragma unroll
            for (int k = 0; k < 9; ++k) {
                float4 a4 = *(const float4*)&A[cc][k][px0];
                const float* wr = wt + ((c0 + cc) * KK + k) * COUT + co0;
                float4 w0 = *(const float4*)wr;
                float4 w1 = *(const float4*)(wr + 4);
                float a[4] = {a4.x, a4.y, a4.z, a4.w};
                float w[8] = {w0.x, w0.y, w0.z, w0.w, w1.x, w1.y, w1.z, w1.w};
#pragma unroll
                for (int i = 0; i < 4; ++i)
#pragma unroll
                    for (int j = 0; j < 8; ++j) acc[i][j] += a[i] * w[j];
            }
        }
        __syncthreads();
    }

    // ---- epilogue ----
#pragma unroll
    for (int j = 0; j < 8; ++j) {
        float bv = bias[co0 + j];
        float4 o;
        o.x = acc[0][j] + bv;
        o.y = acc[1][j] + bv;
        o.z = acc[2][j] + bv;
        o.w = acc[3][j] + bv;
        *(float4*)&out[((size_t)(b * COUT + co0 + j) * HH + y) * WW + x0 + px0] = o;
    }
}

// ---------------------------------------------------------------------------
extern "C" void kernel_launch(void* const* d_in, const int* in_sizes, int n_in,
                              void* d_out, int out_size, void* d_ws, size_t ws_size,
                              hipStream_t stream)
{
    const float* x  = (const float*)d_in[0];
    const float* ow = (const float*)d_in[1];
    const float* ob = (const float*)d_in[2];
    const float* dw = (const float*)d_in[3];
    const float* db = (const float*)d_in[4];
    float* out = (float*)d_out;

    float* offs = (float*)d_ws;                         // 4*18*4096 = 294912 f
    float* wt   = offs + (size_t)BB * OC2 * HH * WW;    // 589824 f  (total ~3.5 MB)

    hipLaunchKernelGGL(wt_transpose_kernel, dim3((COUT * CIN * KK + 255) / 256), dim3(256),
                       0, stream, dw, wt);
    hipLaunchKernelGGL(offset_conv_kernel, dim3(BB * 64), dim3(256), 0, stream, x, ow, ob, offs);
    hipLaunchKernelGGL(dcn_main_kernel, dim3(BB * 128), dim3(256), 0, stream, x, offs, wt, db, out);
}

// Round 2
// 325.564 us; speedup vs baseline: 2.0133x; 2.0133x over previous
//
#include <hip/hip_runtime.h>

#define BB 4
#define CIN 256
#define COUT 256
#define HH 64
#define WW 64
#define KK 9
#define OC2 18
#define KTOT (CIN * KK)        // 2304
#define NSTEP (KTOT / 32)      // 72 MFMA k-steps

typedef __attribute__((ext_vector_type(8))) short bf16x8;
typedef __attribute__((ext_vector_type(4))) float f32x4;

__device__ __forceinline__ unsigned short f2bf(float f) {
    union { float f; unsigned u; } v; v.f = f;
    unsigned r = v.u + 0x7FFFu + ((v.u >> 16) & 1u);   // RNE
    return (unsigned short)(r >> 16);
}

// ---------------------------------------------------------------------------
// Kernel 1: pack dcn_w -> bf16 B fragments.
// Word (cotile, t, lane) holds B[k][co] for co = cotile*16+(lane&15),
// k = t*32 + (lane>>4)*8 + j ; k-order: c = k&255, kk = k>>8.
// ---------------------------------------------------------------------------
__global__ __launch_bounds__(256) void pack_b_kernel(
    const float* __restrict__ w, unsigned short* __restrict__ bp)
{
    int wid = blockIdx.x * 256 + threadIdx.x;           // 16*72*64 = 73728 words
    int cotile = wid / (NSTEP * 64);
    int r = wid - cotile * (NSTEP * 64);
    int t = r >> 6, lane = r & 63;
    int co = cotile * 16 + (lane & 15);
    int kbase = t * 32 + ((lane >> 4) & 3) * 8;
    union { unsigned short s[8]; uint4 q; } u;
#pragma unroll
    for (int j = 0; j < 8; ++j) {
        int k = kbase + j;
        int c = k & 255, kk = k >> 8;
        u.s[j] = f2bf(w[co * KTOT + c * KK + kk]);
    }
    *(uint4*)&bp[(size_t)wid * 8] = u.q;
}

// ---------------------------------------------------------------------------
// Kernel 2: offset conv, fp32 (accuracy-critical: feeds sampling positions).
// grid = B*64 (8x8 px tiles), block = 512 (8 waves). Wave w: all 64 px,
// channels w*32..w*32+31, all 18 oc. LDS-broadcast weights; LDS reduce.
// ---------------------------------------------------------------------------
__global__ __launch_bounds__(512) void offset_conv2_kernel(
    const float* __restrict__ x, const float* __restrict__ ow,
    const float* __restrict__ ob, float* __restrict__ offs)
{
    const int tid  = threadIdx.x;
    const int wv   = tid >> 6;
    const int lane = tid & 63;
    const int blk  = blockIdx.x;
    const int b    = blk >> 6;
    const int tile = blk & 63;
    const int ty0 = (tile >> 3) << 3, tx0 = (tile & 7) << 3;
    const int py = lane >> 3, px = lane & 7;
    const int gy = ty0 + py, gx = tx0 + px;

    __shared__ float wl[8][162];        // per-wave weight slice for current c
    __shared__ float red[8][64][18];    // partials

    float acc[18];
#pragma unroll
    for (int i = 0; i < 18; ++i) acc[i] = 0.f;

    const int cbase = wv * 32;
    for (int cc = 0; cc < 32; ++cc) {
        int c = cbase + cc;
        // stage 162 weights for channel c (this wave's slice)
#pragma unroll
        for (int rr = 0; rr < 3; ++rr) {
            int idx = lane + (rr << 6);
            if (idx < 162) {
                int oc = idx / 9, kk = idx - oc * 9;
                wl[wv][idx] = ow[oc * KTOT + c * KK + kk];
            }
        }
        // 9 x values for this pixel (L1-friendly direct loads)
        const float* xp = x + ((size_t)(b * CIN + c) << 12);
        float xv[9];
#pragma unroll
        for (int kk = 0; kk < 9; ++kk) {
            int ky = kk / 3, kx = kk - 3 * (kk / 3);
            int yy = gy + ky - 1, xx2 = gx + kx - 1;
            bool v = ((unsigned)yy < HH) && ((unsigned)xx2 < WW);
            xv[kk] = v ? xp[(yy << 6) + xx2] : 0.f;
        }
#pragma unroll
        for (int oc = 0; oc < 18; ++oc) {
            float s = acc[oc];
#pragma unroll
            for (int kk = 0; kk < 9; ++kk)
                s += wl[wv][oc * 9 + kk] * xv[kk];
            acc[oc] = s;
        }
    }
#pragma unroll
    for (int oc = 0; oc < 18; ++oc) red[wv][lane][oc] = acc[oc];
    __syncthreads();

    for (int idx = tid; idx < 18 * 64; idx += 512) {
        int oc = idx >> 6, p2 = idx & 63;
        float s = ob[oc];
#pragma unroll
        for (int w2 = 0; w2 < 8; ++w2) s += red[w2][p2][oc];
        int gy2 = ty0 + (p2 >> 3), gx2 = tx0 + (p2 & 7);
        offs[((size_t)(b * OC2 + oc) << 12) + (gy2 << 6) + gx2] = s;
    }
}

// ---------------------------------------------------------------------------
// Kernel 3: fused bilinear-gather + MFMA implicit GEMM.
// 256 blocks: m_blk (128 px = 2 rows) x n0 (128-cout half). 4 waves (2x2),
// wave = 64px x 64co = 4x4 fragments of 16x16x32 bf16 MFMA. Double-buffered
// LDS A (gathered) + B (reg-staged from packed global).
// ---------------------------------------------------------------------------
__global__ __launch_bounds__(256) void dcn_mfma_kernel(
    const float* __restrict__ x, const float* __restrict__ offs,
    const unsigned short* __restrict__ bp, const float* __restrict__ db,
    float* __restrict__ out)
{
    // XCD-aware swizzle (256 blocks, 8 XCDs -> 32 contiguous logical blocks/XCD)
    int P = blockIdx.x;
    int L = (P & 7) * 32 + (P >> 3);
    const int m_blk = L >> 1, n0 = L & 1;
    const int b = m_blk >> 5;
    const int rowbase = (m_blk & 31) * 128;   // px-in-image of block's first pixel

    const int tid = threadIdx.x;
    const int lane = tid & 63, wv = tid >> 6;
    const int wm = wv >> 1, wn = wv & 1;
    const int kgroup = lane >> 4, pin = lane & 15;

    __shared__ unsigned short Asl[2][4096];   // 8 KB per buf
    __shared__ unsigned short Bsl[2][4096];
    __shared__ float4 tw[128 * 9];            // bilinear weights
    __shared__ uint2  ti[128 * 9];            // 4 packed u16 byte-offsets

    // ---- bilinear table for the block's 128 pixels x 9 taps ----
    for (int e = tid; e < 128 * 9; e += 256) {
        int p = e / 9, kk = e - (e / 9) * 9;
        int pxl = rowbase + p;
        int y = pxl >> 6, xx = pxl & 63;
        float dy = offs[((size_t)(b * OC2 + 2 * kk)     << 12) + pxl];
        float dx = offs[((size_t)(b * OC2 + 2 * kk + 1) << 12) + pxl];
        int ky = kk / 3, kx = kk - 3 * (kk / 3);
        float sy = (float)(y - 1 + ky) + dy;
        float sx = (float)(xx - 1 + kx) + dx;
        float fy = floorf(sy), fx = floorf(sx);
        int y0 = (int)fy, x0 = (int)fx;
        float wy1 = sy - fy, wx1 = sx - fx;
        float wy0 = 1.f - wy1, wx0 = 1.f - wx1;
        bool vy0 = (unsigned)y0 < HH, vy1 = (unsigned)(y0 + 1) < HH;
        bool vx0 = (unsigned)x0 < WW, vx1 = (unsigned)(x0 + 1) < WW;
        float4 w4;
        w4.x = (vy0 && vx0) ? wy0 * wx0 : 0.f;
        w4.y = (vy0 && vx1) ? wy0 * wx1 : 0.f;
        w4.z = (vy1 && vx0) ? wy1 * wx0 : 0.f;
        w4.w = (vy1 && vx1) ? wy1 * wx1 : 0.f;
        int y0c = min(max(y0, 0), HH - 1), y1c = min(max(y0 + 1, 0), HH - 1);
        int x0c = min(max(x0, 0), WW - 1), x1c = min(max(x0 + 1, 0), WW - 1);
        unsigned o00 = (unsigned)((y0c * WW + x0c) * 4);
        unsigned o01 = (unsigned)((y0c * WW + x1c) * 4);
        unsigned o10 = (unsigned)((y1c * WW + x0c) * 4);
        unsigned o11 = (unsigned)((y1c * WW + x1c) * 4);
        tw[e] = w4;
        ti[e] = make_uint2(o00 | (o01 << 16), o10 | (o11 << 16));
    }
    __syncthreads();

    const char* xb = (const char*)(x + ((size_t)b * CIN << 12));

    // gather 2 fragment-words (16 patch values) for k-step t into buf
    auto GATHER = [&](int bufi, int t) {
        int kk = t >> 3;                       // tap index, uniform per k-step
        int c0 = (t & 7) * 32 + kgroup * 8;    // first of 8 consecutive channels
#pragma unroll
        for (int i = 0; i < 2; ++i) {
            int mtile = wv + 4 * i;
            int px_loc = mtile * 16 + pin;
            int e = px_loc * 9 + kk;
            float4 w4 = tw[e];
            uint2 t2 = ti[e];
            unsigned o00 = t2.x & 0xFFFFu, o01 = t2.x >> 16;
            unsigned o10 = t2.y & 0xFFFFu, o11 = t2.y >> 16;
            const char* p = xb + ((size_t)c0 << 14);
            union { unsigned short s[8]; uint4 q; } u;
#pragma unroll
            for (int j = 0; j < 8; ++j) {
                float v = w4.x * *(const float*)(p + o00)
                        + w4.y * *(const float*)(p + o01)
                        + w4.z * *(const float*)(p + o10)
                        + w4.w * *(const float*)(p + o11);
                u.s[j] = f2bf(v);
                p += HH * WW * 4;
            }
            *(uint4*)&Asl[bufi][(mtile * 64 + lane) * 8] = u.q;
        }
    };
    auto BLOAD = [&](int t, uint4* breg) {
#pragma unroll
        for (int s = 0; s < 2; ++s) {
            int cot = wv * 2 + s;
            size_t gw = (((size_t)(n0 * 8 + cot) * NSTEP + t) * 64 + lane);
            breg[s] = *(const uint4*)&bp[gw * 8];
        }
    };
    auto BSTORE = [&](int bufi, const uint4* breg) {
#pragma unroll
        for (int s = 0; s < 2; ++s) {
            int cot = wv * 2 + s;
            *(uint4*)&Bsl[bufi][(cot * 64 + lane) * 8] = breg[s];
        }
    };

    f32x4 acc[4][4];
#pragma unroll
    for (int mi = 0; mi < 4; ++mi)
#pragma unroll
        for (int nj = 0; nj < 4; ++nj) {
            f32x4 z = {0.f, 0.f, 0.f, 0.f};
            acc[mi][nj] = z;
        }

    uint4 breg[2];
    BLOAD(0, breg);
    GATHER(0, 0);
    BSTORE(0, breg);
    __syncthreads();

    for (int t = 0; t < NSTEP; ++t) {
        int cur = t & 1, nxt = cur ^ 1;
        if (t + 1 < NSTEP) BLOAD(t + 1, breg);   // long-latency loads in flight
        bf16x8 a[4], bb[4];
#pragma unroll
        for (int mi = 0; mi < 4; ++mi)
            a[mi] = *(const bf16x8*)&Asl[cur][((wm * 4 + mi) * 64 + lane) * 8];
#pragma unroll
        for (int nj = 0; nj < 4; ++nj)
            bb[nj] = *(const bf16x8*)&Bsl[cur][((wn * 4 + nj) * 64 + lane) * 8];
#pragma unroll
        for (int mi = 0; mi < 4; ++mi)
#pragma unroll
            for (int nj = 0; nj < 4; ++nj)
                acc[mi][nj] = __builtin_amdgcn_mfma_f32_16x16x32_bf16(
                    a[mi], bb[nj], acc[mi][nj], 0, 0, 0);
        if (t + 1 < NSTEP) {
            GATHER(nxt, t + 1);                  // VALU overlaps MFMA pipe
            BSTORE(nxt, breg);
        }
        __syncthreads();
    }

    // ---- epilogue: row=(lane>>4)*4+reg -> 4 consecutive px => float4 store ----
    const int rowreg = kgroup * 4;
#pragma unroll
    for (int nj = 0; nj < 4; ++nj) {
        int co = n0 * 128 + wn * 64 + nj * 16 + pin;
        float bv = db[co];
        float* op = out + ((size_t)(b * COUT + co) << 12) + rowbase;
#pragma unroll
        for (int mi = 0; mi < 4; ++mi) {
            int pxoff = wm * 64 + mi * 16 + rowreg;
            float4 o;
            o.x = acc[mi][nj][0] + bv;
            o.y = acc[mi][nj][1] + bv;
            o.z = acc[mi][nj][2] + bv;
            o.w = acc[mi][nj][3] + bv;
            *(float4*)&op[pxoff] = o;
        }
    }
}

// ---------------------------------------------------------------------------
extern "C" void kernel_launch(void* const* d_in, const int* in_sizes, int n_in,
                              void* d_out, int out_size, void* d_ws, size_t ws_size,
                              hipStream_t stream)
{
    const float* x  = (const float*)d_in[0];
    const float* ow = (const float*)d_in[1];
    const float* ob = (const float*)d_in[2];
    const float* dw = (const float*)d_in[3];
    const float* db = (const float*)d_in[4];
    float* out = (float*)d_out;

    float*          offs = (float*)d_ws;                       // 294912 f = 1.125 MB
    unsigned short* bp   = (unsigned short*)((char*)d_ws + (size_t)BB * OC2 * HH * WW * 4);

    hipLaunchKernelGGL(pack_b_kernel, dim3(16 * NSTEP * 64 / 256), dim3(256), 0, stream, dw, bp);
    hipLaunchKernelGGL(offset_conv2_kernel, dim3(BB * 64), dim3(512), 0, stream, x, ow, ob, offs);
    hipLaunchKernelGGL(dcn_mfma_kernel, dim3(256), dim3(256), 0, stream, x, offs, bp, db, out);
}

// Round 3
// 130.859 us; speedup vs baseline: 5.0090x; 2.4879x over previous
//
#include <hip/hip_runtime.h>

#define BB 4
#define CIN 256
#define COUT 256
#define HH 64
#define WW 64
#define KK 9
#define OC2 18
#define KTOT (CIN * KK)        // 2304
#define NSTEP (KTOT / 32)      // 72 MFMA k-steps

typedef __attribute__((ext_vector_type(8))) _Float16 h8;
typedef __attribute__((ext_vector_type(4))) float f32x4;

static __device__ __forceinline__ h8 splat8(_Float16 v) {
    h8 r = {v, v, v, v, v, v, v, v};
    return r;
}

// ---------------------------------------------------------------------------
// Kernel 1: pack dcn_w -> fp16 B fragments. Word (cotile, t, lane):
// co = cotile*16+(lane&15), k = t*32+(lane>>4)*8+j ; k = kk*256 + c.
// ---------------------------------------------------------------------------
__global__ __launch_bounds__(256) void pack_b_kernel(
    const float* __restrict__ w, _Float16* __restrict__ bp)
{
    int wid = blockIdx.x * 256 + threadIdx.x;           // 16*72*64 = 73728 words
    int cotile = wid / (NSTEP * 64);
    int r = wid - cotile * (NSTEP * 64);
    int t = r >> 6, lane = r & 63;
    int co = cotile * 16 + (lane & 15);
    int kbase = t * 32 + ((lane >> 4) & 3) * 8;
    union { _Float16 h[8]; uint4 q; } u;
#pragma unroll
    for (int j = 0; j < 8; ++j) {
        int k = kbase + j;
        int c = k & 255, kk = k >> 8;
        u.h[j] = (_Float16)w[co * KTOT + c * KK + kk];
    }
    *(uint4*)&bp[(size_t)wid * 8] = u.q;
}

// ---------------------------------------------------------------------------
// Kernel 2: pack offset_w -> fp16 B fragments, oc padded 18 -> 32.
// word wid = (t*2 + nj)*64 + lane ; oc = nj*16+(lane&15).
// ---------------------------------------------------------------------------
__global__ __launch_bounds__(256) void pack_ow_kernel(
    const float* __restrict__ ow, _Float16* __restrict__ bow)
{
    int wid = blockIdx.x * 256 + threadIdx.x;           // 72*2*64 = 9216 words
    int t = wid >> 7;
    int r = wid & 127;
    int lane = r & 63;
    int oc = ((r >> 6) << 4) + (lane & 15);
    int kbase = t * 32 + ((lane >> 4) & 3) * 8;
    union { _Float16 h[8]; uint4 q; } u;
#pragma unroll
    for (int j = 0; j < 8; ++j) {
        int k = kbase + j;
        int c = k & 255, kk = k >> 8;
        u.h[j] = (oc < OC2) ? (_Float16)ow[oc * KTOT + c * KK + kk] : (_Float16)0.f;
    }
    *(uint4*)&bow[(size_t)wid * 8] = u.q;
}

// ---------------------------------------------------------------------------
// Kernel 3: transpose x [B][C][H][W] f32 -> xT [B][C/8][H][W][8c] f16.
// grid = B*H (one image row per block), 256 threads.
// ---------------------------------------------------------------------------
__global__ __launch_bounds__(256) void transpose_kernel(
    const float* __restrict__ x, _Float16* __restrict__ xT)
{
    const int blk = blockIdx.x;
    const int b = blk >> 6, y = blk & 63;
    const int t = threadIdx.x;
    __shared__ float tile[64][65];

    for (int c0 = 0; c0 < CIN; c0 += 64) {
#pragma unroll
        for (int r = 0; r < 16; ++r) {
            int idx = r * 256 + t;
            int c = idx >> 6, w = idx & 63;
            tile[c][w] = x[(((size_t)(b * CIN + c0 + c)) << 12) + (y << 6) + w];
        }
        __syncthreads();
#pragma unroll
        for (int half = 0; half < 2; ++half) {
            int cg_l = (t >> 6) + 4 * half;      // 0..7 within this c0 chunk
            int xx = t & 63;
            union { _Float16 h[8]; uint4 q; } u;
#pragma unroll
            for (int j = 0; j < 8; ++j) u.h[j] = (_Float16)tile[cg_l * 8 + j][xx];
            int cg = (c0 >> 3) + cg_l;
            *(uint4*)&xT[((((size_t)(b * 32 + cg)) << 12) + (y << 6) + xx) * 8] = u.q;
        }
        __syncthreads();
    }
}

// ---------------------------------------------------------------------------
// Kernel 4: offset conv as MFMA GEMM (M=16384 px, N=32 padded, K=2304).
// 256 blocks x 256 thr (4 waves). Tile 64px x 32oc; wave = 16px x 32oc.
// A gathered from xT (shifted taps, zero pad), B direct-to-reg from bow.
// ---------------------------------------------------------------------------
__global__ __launch_bounds__(256) void offset_mfma_kernel(
    const _Float16* __restrict__ xT, const _Float16* __restrict__ bow,
    const float* __restrict__ ob, float* __restrict__ offs)
{
    const int blk = blockIdx.x;           // 256
    const int b = blk >> 6;
    const int pxbase = (blk & 63) * 64;
    const int tid = threadIdx.x;
    const int lane = tid & 63, wv = tid >> 6;
    const int pin = lane & 15, kg = lane >> 4;

    __shared__ __align__(16) _Float16 Asl[2][2048];   // 256 words/buf

    const _Float16* xb = xT + ((size_t)b << 20);

    auto GATHER = [&](int bufi, int t) {
        int kk = t >> 3;
        int ky = kk / 3, kx = kk - 3 * (kk / 3);
        int cg = (t & 7) * 4 + kg;
        int px_loc = ((tid >> 6) << 4) + pin;         // mtile = tid>>6
        int pxl = pxbase + px_loc;
        int yy = (pxl >> 6) + ky - 1;
        int xx = (pxl & 63) + kx - 1;
        h8 v = splat8((_Float16)0.f);
        if ((unsigned)yy < HH && (unsigned)xx < WW)
            v = *(const h8*)(xb + (((size_t)cg << 12) + (yy << 6) + xx) * 8);
        *(h8*)&Asl[bufi][tid * 8] = v;
    };

    f32x4 acc[2];
#pragma unroll
    for (int nj = 0; nj < 2; ++nj) { f32x4 z = {0.f,0.f,0.f,0.f}; acc[nj] = z; }

    GATHER(0, 0);
    __syncthreads();

    for (int t = 0; t < NSTEP; ++t) {
        int cur = t & 1;
        union { uint4 q; h8 h; } breg[2];
#pragma unroll
        for (int nj = 0; nj < 2; ++nj)
            breg[nj].q = *(const uint4*)&bow[(size_t)(((t << 1) + nj) * 64 + lane) * 8];
        if (t + 1 < NSTEP) GATHER(cur ^ 1, t + 1);
        h8 a = *(const h8*)&Asl[cur][(wv * 64 + lane) * 8];
#pragma unroll
        for (int nj = 0; nj < 2; ++nj)
            acc[nj] = __builtin_amdgcn_mfma_f32_16x16x32_f16(a, breg[nj].h, acc[nj], 0, 0, 0);
        __syncthreads();
    }

    const int pxb = pxbase + wv * 16 + kg * 4;
#pragma unroll
    for (int nj = 0; nj < 2; ++nj) {
        int oc = nj * 16 + pin;
        if (oc < OC2) {
            float bv = ob[oc];
            float4 o;
            o.x = acc[nj][0] + bv;
            o.y = acc[nj][1] + bv;
            o.z = acc[nj][2] + bv;
            o.w = acc[nj][3] + bv;
            *(float4*)&offs[((size_t)(b * OC2 + oc) << 12) + pxb] = o;
        }
    }
}

// ---------------------------------------------------------------------------
// Kernel 5: fused bilinear-gather + MFMA implicit GEMM (fp16).
// 512 blocks: tile 128px x 64co. 4 waves (2M x 2N): wave 64px x 32co (4x2).
// A gathered to LDS (double buf); B direct global->reg. Bilinear table in LDS.
// ---------------------------------------------------------------------------
__global__ __launch_bounds__(256) void dcn_mfma_kernel(
    const _Float16* __restrict__ xT, const float* __restrict__ offs,
    const _Float16* __restrict__ bp, const float* __restrict__ db,
    float* __restrict__ out)
{
    int P = blockIdx.x;
    int L = (P & 7) * 64 + (P >> 3);      // XCD swizzle: 64 consecutive L per XCD
    const int m_blk = L >> 2, n0 = L & 3;
    const int b = m_blk >> 5;
    const int rowbase = (m_blk & 31) * 128;

    const int tid = threadIdx.x;
    const int lane = tid & 63, wv = tid >> 6;
    const int wm = wv >> 1, wn = wv & 1;
    const int kg = lane >> 4, pin = lane & 15;

    __shared__ __align__(16) _Float16 Asl[2][4096];   // 512 words/buf (8 KB)
    __shared__ uint2 twh[1152];   // 4 fp16 bilinear weights per (px,kk)
    __shared__ uint2 tih[1152];   // 4 u16 pixel indices per (px,kk)

    for (int e = tid; e < 1152; e += 256) {
        int p = e / 9, kk = e - (e / 9) * 9;
        int pxl = rowbase + p;
        int y = pxl >> 6, xx = pxl & 63;
        float dy = offs[((size_t)(b * OC2 + 2 * kk)     << 12) + pxl];
        float dx = offs[((size_t)(b * OC2 + 2 * kk + 1) << 12) + pxl];
        int ky = kk / 3, kx = kk - 3 * (kk / 3);
        float sy = (float)(y - 1 + ky) + dy;
        float sx = (float)(xx - 1 + kx) + dx;
        float fy = floorf(sy), fx = floorf(sx);
        int y0 = (int)fy, x0 = (int)fx;
        float wy1 = sy - fy, wx1 = sx - fx;
        float wy0 = 1.f - wy1, wx0 = 1.f - wx1;
        bool vy0 = (unsigned)y0 < HH, vy1 = (unsigned)(y0 + 1) < HH;
        bool vx0 = (unsigned)x0 < WW, vx1 = (unsigned)(x0 + 1) < WW;
        union { _Float16 h[4]; uint2 u; } W;
        W.h[0] = (_Float16)((vy0 && vx0) ? wy0 * wx0 : 0.f);
        W.h[1] = (_Float16)((vy0 && vx1) ? wy0 * wx1 : 0.f);
        W.h[2] = (_Float16)((vy1 && vx0) ? wy1 * wx0 : 0.f);
        W.h[3] = (_Float16)((vy1 && vx1) ? wy1 * wx1 : 0.f);
        twh[e] = W.u;
        int y0c = min(max(y0, 0), HH - 1), y1c = min(max(y0 + 1, 0), HH - 1);
        int x0c = min(max(x0, 0), WW - 1), x1c = min(max(x0 + 1, 0), WW - 1);
        unsigned i00 = (unsigned)((y0c << 6) + x0c);
        unsigned i01 = (unsigned)((y0c << 6) + x1c);
        unsigned i10 = (unsigned)((y1c << 6) + x0c);
        unsigned i11 = (unsigned)((y1c << 6) + x1c);
        tih[e] = make_uint2(i00 | (i01 << 16), i10 | (i11 << 16));
    }
    __syncthreads();

    const _Float16* xb = xT + ((size_t)b << 20);

    auto GATHER = [&](int bufi, int t) {
        int kk = t >> 3;
        int cg = (t & 7) * 4 + kg;
        const _Float16* slab = xb + ((size_t)cg << 15);
#pragma unroll
        for (int i = 0; i < 2; ++i) {
            int mtile = wv + 4 * i;
            int e = (mtile * 16 + pin) * 9 + kk;
            union { _Float16 h[4]; uint2 u; } W; W.u = twh[e];
            uint2 t2 = tih[e];
            const h8* p00 = (const h8*)(slab + (size_t)(t2.x & 0xFFFFu) * 8);
            const h8* p01 = (const h8*)(slab + (size_t)(t2.x >> 16) * 8);
            const h8* p10 = (const h8*)(slab + (size_t)(t2.y & 0xFFFFu) * 8);
            const h8* p11 = (const h8*)(slab + (size_t)(t2.y >> 16) * 8);
            h8 c00 = *p00, c01 = *p01, c10 = *p10, c11 = *p11;
            h8 v = c00 * splat8(W.h[0]);
            v += c01 * splat8(W.h[1]);
            v += c10 * splat8(W.h[2]);
            v += c11 * splat8(W.h[3]);
            *(h8*)&Asl[bufi][(mtile * 64 + lane) * 8] = v;
        }
    };

    auto BLOAD = [&](int t, uint4* breg) {
#pragma unroll
        for (int nj = 0; nj < 2; ++nj) {
            size_t w = (((size_t)(n0 * 4 + wn * 2 + nj) * NSTEP + t) * 64 + lane);
            breg[nj] = *(const uint4*)&bp[w * 8];
        }
    };

    f32x4 acc[4][2];
#pragma unroll
    for (int mi = 0; mi < 4; ++mi)
#pragma unroll
        for (int nj = 0; nj < 2; ++nj) { f32x4 z = {0.f,0.f,0.f,0.f}; acc[mi][nj] = z; }

    uint4 breg[2], bnext[2];
    GATHER(0, 0);
    BLOAD(0, breg);
    __syncthreads();

    for (int t = 0; t < NSTEP; ++t) {
        int cur = t & 1;
        if (t + 1 < NSTEP) {
            BLOAD(t + 1, bnext);
            GATHER(cur ^ 1, t + 1);
        }
        h8 a[4];
#pragma unroll
        for (int mi = 0; mi < 4; ++mi)
            a[mi] = *(const h8*)&Asl[cur][((wm * 4 + mi) * 64 + lane) * 8];
        union { uint4 q; h8 h; } bb[2];
        bb[0].q = breg[0]; bb[1].q = breg[1];
#pragma unroll
        for (int mi = 0; mi < 4; ++mi)
#pragma unroll
            for (int nj = 0; nj < 2; ++nj)
                acc[mi][nj] = __builtin_amdgcn_mfma_f32_16x16x32_f16(
                    a[mi], bb[nj].h, acc[mi][nj], 0, 0, 0);
        __syncthreads();
        breg[0] = bnext[0]; breg[1] = bnext[1];
    }

#pragma unroll
    for (int nj = 0; nj < 2; ++nj) {
        int co = n0 * 64 + wn * 32 + nj * 16 + pin;
        float bv = db[co];
        float* op = out + ((size_t)(b * COUT + co) << 12) + rowbase;
#pragma unroll
        for (int mi = 0; mi < 4; ++mi) {
            int pxoff = wm * 64 + mi * 16 + kg * 4;
            float4 o;
            o.x = acc[mi][nj][0] + bv;
            o.y = acc[mi][nj][1] + bv;
            o.z = acc[mi][nj][2] + bv;
            o.w = acc[mi][nj][3] + bv;
            *(float4*)&op[pxoff] = o;
        }
    }
}

// ---------------------------------------------------------------------------
extern "C" void kernel_launch(void* const* d_in, const int* in_sizes, int n_in,
                              void* d_out, int out_size, void* d_ws, size_t ws_size,
                              hipStream_t stream)
{
    const float* x  = (const float*)d_in[0];
    const float* ow = (const float*)d_in[1];
    const float* ob = (const float*)d_in[2];
    const float* dw = (const float*)d_in[3];
    const float* db = (const float*)d_in[4];
    float* out = (float*)d_out;

    // workspace layout (bytes): offs f32 1179648 | bp f16 1179648 | bow f16 147456 | xT f16 8388608
    char* wsp = (char*)d_ws;
    float*     offs = (float*)wsp;
    _Float16*  bp   = (_Float16*)(wsp + 1179648);
    _Float16*  bow  = (_Float16*)(wsp + 2359296);
    _Float16*  xT   = (_Float16*)(wsp + 2506752);

    hipLaunchKernelGGL(pack_b_kernel,    dim3(288), dim3(256), 0, stream, dw, bp);
    hipLaunchKernelGGL(pack_ow_kernel,   dim3(36),  dim3(256), 0, stream, ow, bow);
    hipLaunchKernelGGL(transpose_kernel, dim3(BB * HH), dim3(256), 0, stream, x, xT);
    hipLaunchKernelGGL(offset_mfma_kernel, dim3(256), dim3(256), 0, stream, xT, bow, ob, offs);
    hipLaunchKernelGGL(dcn_mfma_kernel,  dim3(512), dim3(256), 0, stream, xT, offs, bp, db, out);
}

// Round 4
// 101.269 us; speedup vs baseline: 6.4726x; 1.2922x over previous
//
#include <hip/hip_runtime.h>

#define BB 4
#define CIN 256
#define COUT 256
#define HH 64
#define WW 64
#define KK 9
#define OC2 18
#define KTOT (CIN * KK)        // 2304
#define NSTEP (KTOT / 32)      // 72 32-k steps
#define NSTAGE (KTOT / 64)     // 36 64-k stages (main kernel)

typedef __attribute__((ext_vector_type(8))) _Float16 h8;
typedef __attribute__((ext_vector_type(4))) float f32x4;

static __device__ __forceinline__ h8 splat_pk(unsigned pk) {
    union { unsigned u[4]; h8 h; } s;
    s.u[0] = pk; s.u[1] = pk; s.u[2] = pk; s.u[3] = pk;
    return s.h;
}

// ---------------------------------------------------------------------------
// Kernel 1: pack dcn_w -> fp16 B fragments, stage-major layout:
// word wid = (t*16 + cotile)*64 + lane ; t = 32-k step, cotile 0..15.
// co = cotile*16+(lane&15) ; k = t*32+((lane>>4)&3)*8+j ; k = kk*256+c.
// ---------------------------------------------------------------------------
__global__ __launch_bounds__(256) void pack_b_kernel(
    const float* __restrict__ w, _Float16* __restrict__ bp)
{
    int wid = blockIdx.x * 256 + threadIdx.x;           // 72*16*64 = 73728 words
    int t = wid >> 10;
    int r = wid & 1023;
    int cotile = r >> 6, lane = r & 63;
    int co = cotile * 16 + (lane & 15);
    int kbase = t * 32 + ((lane >> 4) & 3) * 8;
    union { _Float16 h[8]; uint4 q; } u;
#pragma unroll
    for (int j = 0; j < 8; ++j) {
        int k = kbase + j;
        int c = k & 255, kk = k >> 8;
        u.h[j] = (_Float16)w[co * KTOT + c * KK + kk];
    }
    *(uint4*)&bp[(size_t)wid * 8] = u.q;
}

// ---------------------------------------------------------------------------
// Kernel 2: pack offset_w -> fp16 B fragments, oc padded 18 -> 32.
// word wid = (t*2 + nj)*64 + lane ; oc = nj*16+(lane&15).
// ---------------------------------------------------------------------------
__global__ __launch_bounds__(256) void pack_ow_kernel(
    const float* __restrict__ ow, _Float16* __restrict__ bow)
{
    int wid = blockIdx.x * 256 + threadIdx.x;           // 72*2*64 = 9216 words
    int t = wid >> 7;
    int r = wid & 127;
    int lane = r & 63;
    int oc = ((r >> 6) << 4) + (lane & 15);
    int kbase = t * 32 + ((lane >> 4) & 3) * 8;
    union { _Float16 h[8]; uint4 q; } u;
#pragma unroll
    for (int j = 0; j < 8; ++j) {
        int k = kbase + j;
        int c = k & 255, kk = k >> 8;
        u.h[j] = (oc < OC2) ? (_Float16)ow[oc * KTOT + c * KK + kk] : (_Float16)0.f;
    }
    *(uint4*)&bow[(size_t)wid * 8] = u.q;
}

// ---------------------------------------------------------------------------
// Kernel 3: transpose x [B][C][H][W] f32 -> xT [B][C/8][H][W][8c] f16.
// ---------------------------------------------------------------------------
__global__ __launch_bounds__(256) void transpose_kernel(
    const float* __restrict__ x, _Float16* __restrict__ xT)
{
    const int blk = blockIdx.x;
    const int b = blk >> 6, y = blk & 63;
    const int t = threadIdx.x;
    __shared__ float tile[64][65];

    for (int c0 = 0; c0 < CIN; c0 += 64) {
#pragma unroll
        for (int r = 0; r < 16; ++r) {
            int idx = r * 256 + t;
            int c = idx >> 6, w = idx & 63;
            tile[c][w] = x[(((size_t)(b * CIN + c0 + c)) << 12) + (y << 6) + w];
        }
        __syncthreads();
#pragma unroll
        for (int half = 0; half < 2; ++half) {
            int cg_l = (t >> 6) + 4 * half;
            int xx = t & 63;
            union { _Float16 h[8]; uint4 q; } u;
#pragma unroll
            for (int j = 0; j < 8; ++j) u.h[j] = (_Float16)tile[cg_l * 8 + j][xx];
            int cg = (c0 >> 3) + cg_l;
            *(uint4*)&xT[((((size_t)(b * 32 + cg)) << 12) + (y << 6) + xx) * 8] = u.q;
        }
        __syncthreads();
    }
}

// ---------------------------------------------------------------------------
// Kernel 4: offset conv MFMA GEMM, K-split x2 with f32 atomic accumulate.
// grid = 512: m_blk = bid>>1 (64px tile), kh = bid&1 (K half).
// offs must be zeroed beforehand; kh==0 adds bias.
// ---------------------------------------------------------------------------
__global__ __launch_bounds__(256) void offset_mfma_kernel(
    const _Float16* __restrict__ xT, const _Float16* __restrict__ bow,
    const float* __restrict__ ob, float* __restrict__ offs)
{
    const int bid = blockIdx.x;
    const int m_blk = bid >> 1, kh = bid & 1;
    const int b = m_blk >> 6;
    const int pxbase = (m_blk & 63) * 64;
    const int tid = threadIdx.x;
    const int lane = tid & 63, wv = tid >> 6;
    const int pin = lane & 15, kg = lane >> 4;

    __shared__ __align__(16) _Float16 Asl[2][2048];

    const _Float16* xb = xT + ((size_t)b << 20);

    auto GATHER = [&](int bufi, int t) {
        int kk = t >> 3;
        int ky = kk / 3, kx = kk - 3 * (kk / 3);
        int cg = (t & 7) * 4 + kg;
        int px_loc = ((tid >> 6) << 4) + pin;
        int pxl = pxbase + px_loc;
        int yy = (pxl >> 6) + ky - 1;
        int xx = (pxl & 63) + kx - 1;
        h8 v = {0,0,0,0,0,0,0,0};
        if ((unsigned)yy < HH && (unsigned)xx < WW)
            v = *(const h8*)(xb + (((size_t)cg << 12) + (yy << 6) + xx) * 8);
        *(h8*)&Asl[bufi][tid * 8] = v;
    };

    f32x4 acc[2];
#pragma unroll
    for (int nj = 0; nj < 2; ++nj) { f32x4 z = {0.f,0.f,0.f,0.f}; acc[nj] = z; }

    const int t0 = kh * 36, t1 = t0 + 36;
    GATHER(0, t0);
    __syncthreads();

    for (int t = t0; t < t1; ++t) {
        int cur = t & 1;
        union { uint4 q; h8 h; } breg[2];
#pragma unroll
        for (int nj = 0; nj < 2; ++nj)
            breg[nj].q = *(const uint4*)&bow[(size_t)(((t << 1) + nj) * 64 + lane) * 8];
        if (t + 1 < t1) GATHER(cur ^ 1, t + 1);
        h8 a = *(const h8*)&Asl[cur][(wv * 64 + lane) * 8];
#pragma unroll
        for (int nj = 0; nj < 2; ++nj)
            acc[nj] = __builtin_amdgcn_mfma_f32_16x16x32_f16(a, breg[nj].h, acc[nj], 0, 0, 0);
        __syncthreads();
    }

    const int pxb = pxbase + wv * 16 + kg * 4;
#pragma unroll
    for (int nj = 0; nj < 2; ++nj) {
        int oc = nj * 16 + pin;
        if (oc < OC2) {
            float bv = (kh == 0) ? ob[oc] : 0.f;
            float* dst = &offs[((size_t)(b * OC2 + oc) << 12) + pxb];
            atomicAdd(dst + 0, acc[nj][0] + bv);
            atomicAdd(dst + 1, acc[nj][1] + bv);
            atomicAdd(dst + 2, acc[nj][2] + bv);
            atomicAdd(dst + 3, acc[nj][3] + bv);
        }
    }
}

// ---------------------------------------------------------------------------
// Kernel 5: fused bilinear-gather + MFMA implicit GEMM (fp16), v3.
// 512 blocks = 256 m (64px = one image row) x 2 n (128co). 512 thr = 8 waves
// (2M x 4N): wave = 32px x 32co (2x2 frags, 2 k-substeps => 8 MFMA/stage).
// BK=64 stages (36 barriers). Gather addressing hoisted per kk-group
// (reload every 4 stages; +512KB pointer bump per stage otherwise).
// ---------------------------------------------------------------------------
__global__ __launch_bounds__(512, 4) void dcn_mfma_kernel(
    const _Float16* __restrict__ xT, const float* __restrict__ offs,
    const _Float16* __restrict__ bp, const float* __restrict__ db,
    float* __restrict__ out)
{
    int P = blockIdx.x;
    int L = (P & 7) * 64 + (P >> 3);      // XCD swizzle: 64 consecutive L per XCD
    const int m_blk = L >> 1, n0 = L & 1;
    const int b = m_blk >> 6;
    const int rowbase = (m_blk & 63) * 64;    // one image row

    const int tid = threadIdx.x;
    const int lane = tid & 63;
    const int wv = tid >> 6;                  // 0..7
    const int wm = wv >> 2, wn = wv & 3;      // 2M x 4N
    const int kg = (lane >> 4) & 3, pin = lane & 15;

    // gather role: word id = tid
    const int g_pin = tid & 15;
    const int g_kg = (tid >> 4) & 3;
    const int g_mtile = (tid >> 6) & 3;
    const int g_ksub = tid >> 8;              // 0..1

    __shared__ __align__(16) _Float16 Asl[2][4096];  // 8 KB per buf
    __shared__ __align__(16) uint4 tw4[576];         // 4 dup-packed fp16 weights
    __shared__ __align__(16) uint2 tih[576];         // 4 u16 pixel indices

    // ---- bilinear table: 64 px x 9 taps ----
    for (int e = tid; e < 576; e += 512) {
        int p = e / 9, kk = e - (e / 9) * 9;
        int pxl = rowbase + p;
        int y = pxl >> 6, xx = pxl & 63;
        float dy = offs[((size_t)(b * OC2 + 2 * kk)     << 12) + pxl];
        float dx = offs[((size_t)(b * OC2 + 2 * kk + 1) << 12) + pxl];
        int ky = kk / 3, kx = kk - 3 * (kk / 3);
        float sy = (float)(y - 1 + ky) + dy;
        float sx = (float)(xx - 1 + kx) + dx;
        float fy = floorf(sy), fx = floorf(sx);
        int y0 = (int)fy, x0 = (int)fx;
        float wy1 = sy - fy, wx1 = sx - fx;
        float wy0 = 1.f - wy1, wx0 = 1.f - wx1;
        bool vy0 = (unsigned)y0 < HH, vy1 = (unsigned)(y0 + 1) < HH;
        bool vx0 = (unsigned)x0 < WW, vx1 = (unsigned)(x0 + 1) < WW;
        _Float16 w00 = (_Float16)((vy0 && vx0) ? wy0 * wx0 : 0.f);
        _Float16 w01 = (_Float16)((vy0 && vx1) ? wy0 * wx1 : 0.f);
        _Float16 w10 = (_Float16)((vy1 && vx0) ? wy1 * wx0 : 0.f);
        _Float16 w11 = (_Float16)((vy1 && vx1) ? wy1 * wx1 : 0.f);
        union { _Float16 h[2]; unsigned u; } pk;
        uint4 W;
        pk.h[0] = w00; pk.h[1] = w00; W.x = pk.u;
        pk.h[0] = w01; pk.h[1] = w01; W.y = pk.u;
        pk.h[0] = w10; pk.h[1] = w10; W.z = pk.u;
        pk.h[0] = w11; pk.h[1] = w11; W.w = pk.u;
        tw4[e] = W;
        int y0c = min(max(y0, 0), HH - 1), y1c = min(max(y0 + 1, 0), HH - 1);
        int x0c = min(max(x0, 0), WW - 1), x1c = min(max(x0 + 1, 0), WW - 1);
        unsigned i00 = (unsigned)((y0c << 6) + x0c);
        unsigned i01 = (unsigned)((y0c << 6) + x1c);
        unsigned i10 = (unsigned)((y1c << 6) + x0c);
        unsigned i11 = (unsigned)((y1c << 6) + x1c);
        tih[e] = make_uint2(i00 | (i01 << 16), i10 | (i11 << 16));
    }

    const char* xbyte = (const char*)(xT + ((size_t)b << 20));

    // persistent gather state (valid for current gather stage)
    uint4 wq = {0, 0, 0, 0};
    const char *p0 = xbyte, *p1 = xbyte, *p2 = xbyte, *p3 = xbyte;

    __syncthreads();   // table visible

    // gather one A word (8 ch) for stage gs into buf; maintains hoisted state
    auto GATHER = [&](int bufi, int gs) {
        if ((gs & 3) == 0) {                  // kk-group reload
            int kk = gs >> 2;
            int e = (g_mtile * 16 + g_pin) * 9 + kk;
            wq = tw4[e];
            uint2 ij = tih[e];
            const char* base = xbyte + (((size_t)(g_ksub * 4 + g_kg)) << 16);
            p0 = base + (size_t)(ij.x & 0xFFFFu) * 16;
            p1 = base + (size_t)(ij.x >> 16)     * 16;
            p2 = base + (size_t)(ij.y & 0xFFFFu) * 16;
            p3 = base + (size_t)(ij.y >> 16)     * 16;
        }
        h8 c00 = *(const h8*)p0;
        h8 c01 = *(const h8*)p1;
        h8 c10 = *(const h8*)p2;
        h8 c11 = *(const h8*)p3;
        h8 v = c00 * splat_pk(wq.x);
        v += c01 * splat_pk(wq.y);
        v += c10 * splat_pk(wq.z);
        v += c11 * splat_pk(wq.w);
        *(h8*)&Asl[bufi][tid * 8] = v;
        p0 += 524288; p1 += 524288; p2 += 524288; p3 += 524288;   // next stage (+8 slabs)
    };

    // B: 4 words per thread per stage (2 ksub x 2 nj)
    auto BLOAD = [&](int st, uint4* br) {
#pragma unroll
        for (int ks = 0; ks < 2; ++ks)
#pragma unroll
            for (int nj = 0; nj < 2; ++nj) {
                size_t word = ((size_t)((st * 2 + ks) * 16 + n0 * 8 + wn * 2 + nj)) * 64 + lane;
                br[ks * 2 + nj] = *(const uint4*)&bp[word * 8];
            }
    };

    f32x4 acc[2][2];
#pragma unroll
    for (int mi = 0; mi < 2; ++mi)
#pragma unroll
        for (int nj = 0; nj < 2; ++nj) { f32x4 z = {0.f,0.f,0.f,0.f}; acc[mi][nj] = z; }

    uint4 breg[4], bnext[4];
    GATHER(0, 0);
    BLOAD(0, breg);
    __syncthreads();

    for (int st = 0; st < NSTAGE; ++st) {
        int cur = st & 1;
        if (st + 1 < NSTAGE) {
            BLOAD(st + 1, bnext);
            GATHER(cur ^ 1, st + 1);
        }
        h8 a[2][2];
#pragma unroll
        for (int ks = 0; ks < 2; ++ks)
#pragma unroll
            for (int mi = 0; mi < 2; ++mi)
                a[ks][mi] = *(const h8*)&Asl[cur][((ks * 4 + wm * 2 + mi) * 64 + lane) * 8];
        union { uint4 q; h8 h; } bb;
#pragma unroll
        for (int ks = 0; ks < 2; ++ks)
#pragma unroll
            for (int nj = 0; nj < 2; ++nj) {
                bb.q = breg[ks * 2 + nj];
#pragma unroll
                for (int mi = 0; mi < 2; ++mi)
                    acc[mi][nj] = __builtin_amdgcn_mfma_f32_16x16x32_f16(
                        a[ks][mi], bb.h, acc[mi][nj], 0, 0, 0);
            }
        __syncthreads();
#pragma unroll
        for (int i = 0; i < 4; ++i) breg[i] = bnext[i];
    }

    // ---- epilogue ----
#pragma unroll
    for (int nj = 0; nj < 2; ++nj) {
        int co = n0 * 128 + wn * 32 + nj * 16 + pin;
        float bv = db[co];
        float* op = out + ((size_t)(b * COUT + co) << 12) + rowbase;
#pragma unroll
        for (int mi = 0; mi < 2; ++mi) {
            int pxoff = (wm * 2 + mi) * 16 + kg * 4;
            float4 o;
            o.x = acc[mi][nj][0] + bv;
            o.y = acc[mi][nj][1] + bv;
            o.z = acc[mi][nj][2] + bv;
            o.w = acc[mi][nj][3] + bv;
            *(float4*)&op[pxoff] = o;
        }
    }
}

// ---------------------------------------------------------------------------
extern "C" void kernel_launch(void* const* d_in, const int* in_sizes, int n_in,
                              void* d_out, int out_size, void* d_ws, size_t ws_size,
                              hipStream_t stream)
{
    const float* x  = (const float*)d_in[0];
    const float* ow = (const float*)d_in[1];
    const float* ob = (const float*)d_in[2];
    const float* dw = (const float*)d_in[3];
    const float* db = (const float*)d_in[4];
    float* out = (float*)d_out;

    // ws layout (bytes): offs f32 1179648 | bp f16 1179648 | bow f16 147456 | xT f16 8388608
    char* wsp = (char*)d_ws;
    float*     offs = (float*)wsp;
    _Float16*  bp   = (_Float16*)(wsp + 1179648);
    _Float16*  bow  = (_Float16*)(wsp + 2359296);
    _Float16*  xT   = (_Float16*)(wsp + 2506752);

    hipMemsetAsync(offs, 0, (size_t)BB * OC2 * HH * WW * sizeof(float), stream);
    hipLaunchKernelGGL(pack_b_kernel,    dim3(288), dim3(256), 0, stream, dw, bp);
    hipLaunchKernelGGL(pack_ow_kernel,   dim3(36),  dim3(256), 0, stream, ow, bow);
    hipLaunchKernelGGL(transpose_kernel, dim3(BB * HH), dim3(256), 0, stream, x, xT);
    hipLaunchKernelGGL(offset_mfma_kernel, dim3(512), dim3(256), 0, stream, xT, bow, ob, offs);
    hipLaunchKernelGGL(dcn_mfma_kernel,  dim3(512), dim3(512), 0, stream, xT, offs, bp, db, out);
}

// Round 5
// 76.982 us; speedup vs baseline: 8.5147x; 1.3155x over previous
//
#include <hip/hip_runtime.h>

#define BB 4
#define CIN 256
#define COUT 256
#define HH 64
#define WW 64
#define KK 9
#define OC2 18
#define KTOT (CIN * KK)        // 2304
#define NSTAGE 36              // 64-k stages (main kernel)

typedef __attribute__((ext_vector_type(8))) _Float16 h8;
typedef __attribute__((ext_vector_type(4))) float f32x4;

static __device__ __forceinline__ h8 splat_pk(unsigned pk) {
    union { unsigned u[4]; h8 h; } s;
    s.u[0] = pk; s.u[1] = pk; s.u[2] = pk; s.u[3] = pk;
    return s.h;
}

// ---------------------------------------------------------------------------
// Kernel 1 (fused prework): transpose x -> xT (1024 blocks), pack dcn_w -> bp
// (288 blocks), pack offset_w -> bow (36 blocks). One launch, 1348 blocks.
// ---------------------------------------------------------------------------
__global__ __launch_bounds__(256) void prework_kernel(
    const float* __restrict__ x, const float* __restrict__ ow,
    const float* __restrict__ dw,
    _Float16* __restrict__ xT, _Float16* __restrict__ bp,
    _Float16* __restrict__ bow)
{
    const int bid = blockIdx.x;
    const int t = threadIdx.x;
    if (bid < 1024) {
        // ---- transpose chunk: (b, y, 64-channel group) ----
        const int b = bid >> 8, y = (bid >> 2) & 63, c0 = (bid & 3) * 64;
        __shared__ float tile[64][65];
#pragma unroll
        for (int r = 0; r < 16; ++r) {
            int idx = r * 256 + t;
            int c = idx >> 6, w = idx & 63;
            tile[c][w] = x[(((size_t)(b * CIN + c0 + c)) << 12) + (y << 6) + w];
        }
        __syncthreads();
#pragma unroll
        for (int half = 0; half < 2; ++half) {
            int cg_l = (t >> 6) + 4 * half, xx = t & 63;
            union { _Float16 h[8]; uint4 q; } u;
#pragma unroll
            for (int j = 0; j < 8; ++j) u.h[j] = (_Float16)tile[cg_l * 8 + j][xx];
            int cg = (c0 >> 3) + cg_l;
            *(uint4*)&xT[((((size_t)(b * 32 + cg)) << 12) + (y << 6) + xx) * 8] = u.q;
        }
    } else if (bid < 1312) {
        // ---- pack dcn_w: word wid = (st*16 + cotile)*64 + lane ----
        int wid = (bid - 1024) * 256 + t;
        int st = wid >> 10;
        int r = wid & 1023;
        int cotile = r >> 6, lane = r & 63;
        int co = cotile * 16 + (lane & 15);
        int kbase = st * 32 + ((lane >> 4) & 3) * 8;
        union { _Float16 h[8]; uint4 q; } u;
#pragma unroll
        for (int j = 0; j < 8; ++j) {
            int k = kbase + j;
            int c = k & 255, kk = k >> 8;
            u.h[j] = (_Float16)dw[co * KTOT + c * KK + kk];
        }
        *(uint4*)&bp[(size_t)wid * 8] = u.q;
    } else {
        // ---- pack offset_w (oc padded 18->32): wid = (st*2+nj)*64+lane ----
        int wid = (bid - 1312) * 256 + t;
        int st = wid >> 7;
        int r = wid & 127;
        int lane = r & 63;
        int oc = ((r >> 6) << 4) + (lane & 15);
        int kbase = st * 32 + ((lane >> 4) & 3) * 8;
        union { _Float16 h[8]; uint4 q; } u;
#pragma unroll
        for (int j = 0; j < 8; ++j) {
            int k = kbase + j;
            int c = k & 255, kk = k >> 8;
            u.h[j] = (oc < OC2) ? (_Float16)ow[oc * KTOT + c * KK + kk] : (_Float16)0.f;
        }
        *(uint4*)&bow[(size_t)wid * 8] = u.q;
    }
}

// ---------------------------------------------------------------------------
// Kernel 2: offset conv MFMA GEMM, split-K=2, each half writes its own fp32
// partial buffer (no atomics, no memset; main kernel sums both halves).
// grid = 512: m_blk = bid>>1 (64px), kh = bid&1. Async-split gather (2-deep).
// ---------------------------------------------------------------------------
__global__ __launch_bounds__(256) void offset_mfma_kernel(
    const _Float16* __restrict__ xT, const _Float16* __restrict__ bow,
    float* __restrict__ opart)
{
    const int bid = blockIdx.x;
    const int m_blk = bid >> 1, kh = bid & 1;
    const int b = m_blk >> 6;
    const int pxbase = (m_blk & 63) * 64;
    const int tid = threadIdx.x;
    const int lane = tid & 63, wv = tid >> 6;
    const int pin = lane & 15, kg = lane >> 4;

    __shared__ __align__(16) _Float16 Asl[2][2048];

    const _Float16* xb = xT + ((size_t)b << 20);
    const int pxl = pxbase + (wv << 4) + pin;
    const int py = pxl >> 6, px = pxl & 63;

    auto GLOAD = [&](int st, h8& R) {
        int kk = st >> 3;
        int ky = kk / 3, kx = kk - 3 * (kk / 3);
        int cg = (st & 7) * 4 + kg;
        int yy = py + ky - 1, xx = px + kx - 1;
        h8 v = {0, 0, 0, 0, 0, 0, 0, 0};
        if ((unsigned)yy < HH && (unsigned)xx < WW)
            v = *(const h8*)(xb + (((size_t)cg << 12) + (yy << 6) + xx) * 8);
        R = v;
    };
    auto BLOAD = [&](int st, uint4* br) {
#pragma unroll
        for (int nj = 0; nj < 2; ++nj)
            br[nj] = *(const uint4*)&bow[(size_t)(((st << 1) + nj) * 64 + lane) * 8];
    };

    f32x4 acc[2];
    {
        f32x4 z = {0.f, 0.f, 0.f, 0.f};
        acc[0] = z; acc[1] = z;
    }

    const int t0 = kh * 36;
    h8 RA, RB;
    uint4 bregA[2], bregB[2];

    GLOAD(t0, RA);
    GLOAD(t0 + 1, RB);
    BLOAD(t0, bregA);
    *(h8*)&Asl[0][tid * 8] = RA;
    __syncthreads();

    for (int tt = 0; tt < 36; tt += 2) {
        int st = t0 + tt;
        // ---- stage tt (buf0, bregA) ----
        if (tt + 2 < 36) GLOAD(st + 2, RA);
        BLOAD(st + 1, bregB);
        {
            h8 a = *(const h8*)&Asl[0][tid * 8];
            union { uint4 q; h8 h; } bb;
#pragma unroll
            for (int nj = 0; nj < 2; ++nj) {
                bb.q = bregA[nj];
                acc[nj] = __builtin_amdgcn_mfma_f32_16x16x32_f16(a, bb.h, acc[nj], 0, 0, 0);
            }
        }
        *(h8*)&Asl[1][tid * 8] = RB;       // waits on RB's load AFTER the MFMAs
        __syncthreads();
        // ---- stage tt+1 (buf1, bregB) ----
        if (tt + 3 < 36) GLOAD(st + 3, RB);
        if (tt + 2 < 36) BLOAD(st + 2, bregA);
        {
            h8 a = *(const h8*)&Asl[1][tid * 8];
            union { uint4 q; h8 h; } bb;
#pragma unroll
            for (int nj = 0; nj < 2; ++nj) {
                bb.q = bregB[nj];
                acc[nj] = __builtin_amdgcn_mfma_f32_16x16x32_f16(a, bb.h, acc[nj], 0, 0, 0);
            }
        }
        if (tt + 2 < 36) *(h8*)&Asl[0][tid * 8] = RA;
        __syncthreads();
    }

    const int pxb = pxbase + (wv << 4) + kg * 4;
#pragma unroll
    for (int nj = 0; nj < 2; ++nj) {
        int oc = nj * 16 + pin;
        if (oc < OC2) {
            float4 o;
            o.x = acc[nj][0]; o.y = acc[nj][1];
            o.z = acc[nj][2]; o.w = acc[nj][3];
            *(float4*)&opart[(((size_t)((kh * BB + b) * OC2 + oc)) << 12) + pxb] = o;
        }
    }
}

// ---------------------------------------------------------------------------
// Kernel 3: fused bilinear-gather + MFMA implicit GEMM (fp16), v4.
// 512 blocks (64px x 128co), 8 waves (2M x 4N), BK=64, 36 stages.
// 2-deep async gather: loads for stage s issued at s-2; pk-fma + ds_write
// happen AFTER the MFMAs (T14 split). Consume-side weights re-read from LDS.
// ---------------------------------------------------------------------------
__global__ __launch_bounds__(512, 4) void dcn_mfma_kernel(
    const _Float16* __restrict__ xT, const float* __restrict__ opart,
    const float* __restrict__ ob, const _Float16* __restrict__ bp,
    const float* __restrict__ db, float* __restrict__ out)
{
    int P = blockIdx.x;
    int L = (P & 7) * 64 + (P >> 3);      // XCD swizzle
    const int m_blk = L >> 1, n0 = L & 1;
    const int b = m_blk >> 6;
    const int rowbase = (m_blk & 63) * 64;

    const int tid = threadIdx.x;
    const int lane = tid & 63;
    const int wv = tid >> 6;
    const int wm = wv >> 2, wn = wv & 3;
    const int kg = (lane >> 4) & 3, pin = lane & 15;

    const int g_pin = tid & 15;
    const int g_kg = (tid >> 4) & 3;
    const int g_mtile = (tid >> 6) & 3;
    const int g_ksub = tid >> 8;
    const int g_ebase = (g_mtile * 16 + g_pin) * 9;

    __shared__ __align__(16) _Float16 Asl[2][4096];  // 8 KB per buf
    __shared__ __align__(16) uint4 tw4[576];
    __shared__ __align__(16) uint2 tih[576];

    // ---- bilinear table (sums the 2 split-K offset partials + bias) ----
    const float* op0 = opart + (((size_t)(b * OC2)) << 12);
    const float* op1 = opart + (((size_t)((BB + b) * OC2)) << 12);
    for (int e = tid; e < 576; e += 512) {
        int p = e / 9, kk = e - (e / 9) * 9;
        int pxl = rowbase + p;
        int y = pxl >> 6, xx = pxl & 63;
        float dy = op0[((size_t)(2 * kk) << 12) + pxl]
                 + op1[((size_t)(2 * kk) << 12) + pxl] + ob[2 * kk];
        float dx = op0[((size_t)(2 * kk + 1) << 12) + pxl]
                 + op1[((size_t)(2 * kk + 1) << 12) + pxl] + ob[2 * kk + 1];
        int ky = kk / 3, kx = kk - 3 * (kk / 3);
        float sy = (float)(y - 1 + ky) + dy;
        float sx = (float)(xx - 1 + kx) + dx;
        float fy = floorf(sy), fx = floorf(sx);
        int y0 = (int)fy, x0 = (int)fx;
        float wy1 = sy - fy, wx1 = sx - fx;
        float wy0 = 1.f - wy1, wx0 = 1.f - wx1;
        bool vy0 = (unsigned)y0 < HH, vy1 = (unsigned)(y0 + 1) < HH;
        bool vx0 = (unsigned)x0 < WW, vx1 = (unsigned)(x0 + 1) < WW;
        _Float16 w00 = (_Float16)((vy0 && vx0) ? wy0 * wx0 : 0.f);
        _Float16 w01 = (_Float16)((vy0 && vx1) ? wy0 * wx1 : 0.f);
        _Float16 w10 = (_Float16)((vy1 && vx0) ? wy1 * wx0 : 0.f);
        _Float16 w11 = (_Float16)((vy1 && vx1) ? wy1 * wx1 : 0.f);
        union { _Float16 h[2]; unsigned u; } pk;
        uint4 W;
        pk.h[0] = w00; pk.h[1] = w00; W.x = pk.u;
        pk.h[0] = w01; pk.h[1] = w01; W.y = pk.u;
        pk.h[0] = w10; pk.h[1] = w10; W.z = pk.u;
        pk.h[0] = w11; pk.h[1] = w11; W.w = pk.u;
        tw4[e] = W;
        int y0c = min(max(y0, 0), HH - 1), y1c = min(max(y0 + 1, 0), HH - 1);
        int x0c = min(max(x0, 0), WW - 1), x1c = min(max(x0 + 1, 0), WW - 1);
        unsigned i00 = (unsigned)((y0c << 6) + x0c);
        unsigned i01 = (unsigned)((y0c << 6) + x1c);
        unsigned i10 = (unsigned)((y1c << 6) + x0c);
        unsigned i11 = (unsigned)((y1c << 6) + x1c);
        tih[e] = make_uint2(i00 | (i01 << 16), i10 | (i11 << 16));
    }
    __syncthreads();

    const char* xbyte = (const char*)(xT + ((size_t)b << 20));
    const char *pL0 = xbyte, *pL1 = xbyte, *pL2 = xbyte, *pL3 = xbyte;

    // issue-only: 4 corner loads for stage gs (sequential gs calls!)
    auto GLOAD = [&](int gs, h8& c00, h8& c01, h8& c10, h8& c11) {
        if ((gs & 3) == 0) {               // new kk group: rebuild pointers
            int e = g_ebase + (gs >> 2);
            uint2 ij = tih[e];
            const char* base = xbyte + (((size_t)(g_ksub * 4 + g_kg)) << 16);
            pL0 = base + (size_t)(ij.x & 0xFFFFu) * 16;
            pL1 = base + (size_t)(ij.x >> 16)     * 16;
            pL2 = base + (size_t)(ij.y & 0xFFFFu) * 16;
            pL3 = base + (size_t)(ij.y >> 16)     * 16;
        }
        c00 = *(const h8*)pL0; c01 = *(const h8*)pL1;
        c10 = *(const h8*)pL2; c11 = *(const h8*)pL3;
        pL0 += 524288; pL1 += 524288; pL2 += 524288; pL3 += 524288;
    };
    // consume: weights re-read from LDS (correct for any lookahead depth)
    auto GCONSUME = [&](int gs, int buf, h8 c00, h8 c01, h8 c10, h8 c11) {
        int e = g_ebase + (gs >> 2);
        uint4 wq = tw4[e];
        h8 v = c00 * splat_pk(wq.x);
        v += c01 * splat_pk(wq.y);
        v += c10 * splat_pk(wq.z);
        v += c11 * splat_pk(wq.w);
        *(h8*)&Asl[buf][tid * 8] = v;
    };
    auto BLOAD = [&](int st, uint4* br) {
#pragma unroll
        for (int ks = 0; ks < 2; ++ks)
#pragma unroll
            for (int nj = 0; nj < 2; ++nj) {
                size_t word = ((size_t)((st * 2 + ks) * 16 + n0 * 8 + wn * 2 + nj)) * 64 + lane;
                br[ks * 2 + nj] = *(const uint4*)&bp[word * 8];
            }
    };

    f32x4 acc[2][2];
#pragma unroll
    for (int mi = 0; mi < 2; ++mi)
#pragma unroll
        for (int nj = 0; nj < 2; ++nj) { f32x4 z = {0.f, 0.f, 0.f, 0.f}; acc[mi][nj] = z; }

    auto MFMA8 = [&](int buf, uint4* br) {
        h8 a[2][2];
#pragma unroll
        for (int ks = 0; ks < 2; ++ks)
#pragma unroll
            for (int mi = 0; mi < 2; ++mi)
                a[ks][mi] = *(const h8*)&Asl[buf][((ks * 4 + wm * 2 + mi) * 64 + lane) * 8];
        union { uint4 q; h8 h; } bb;
#pragma unroll
        for (int ks = 0; ks < 2; ++ks)
#pragma unroll
            for (int nj = 0; nj < 2; ++nj) {
                bb.q = br[ks * 2 + nj];
#pragma unroll
                for (int mi = 0; mi < 2; ++mi)
                    acc[mi][nj] = __builtin_amdgcn_mfma_f32_16x16x32_f16(
                        a[ks][mi], bb.h, acc[mi][nj], 0, 0, 0);
            }
    };

    h8 A0, A1, A2, A3, B0, B1, B2, B3;
    uint4 bregA[4], bregB[4];

    GLOAD(0, A0, A1, A2, A3);
    GLOAD(1, B0, B1, B2, B3);
    BLOAD(0, bregA);
    GCONSUME(0, 0, A0, A1, A2, A3);
    __syncthreads();

    for (int st = 0; st < NSTAGE; st += 2) {
        // ---- stage st (buf0, bregA) ----
        if (st + 2 < NSTAGE) GLOAD(st + 2, A0, A1, A2, A3);
        BLOAD(st + 1, bregB);
        MFMA8(0, bregA);
        GCONSUME(st + 1, 1, B0, B1, B2, B3);   // vm-wait lands AFTER the MFMAs
        __syncthreads();
        // ---- stage st+1 (buf1, bregB) ----
        if (st + 3 < NSTAGE) GLOAD(st + 3, B0, B1, B2, B3);
        if (st + 2 < NSTAGE) BLOAD(st + 2, bregA);
        MFMA8(1, bregB);
        if (st + 2 < NSTAGE) GCONSUME(st + 2, 0, A0, A1, A2, A3);
        __syncthreads();
    }

    // ---- epilogue ----
#pragma unroll
    for (int nj = 0; nj < 2; ++nj) {
        int co = n0 * 128 + wn * 32 + nj * 16 + pin;
        float bv = db[co];
        float* op = out + ((size_t)(b * COUT + co) << 12) + rowbase;
#pragma unroll
        for (int mi = 0; mi < 2; ++mi) {
            int pxoff = (wm * 2 + mi) * 16 + kg * 4;
            float4 o;
            o.x = acc[mi][nj][0] + bv;
            o.y = acc[mi][nj][1] + bv;
            o.z = acc[mi][nj][2] + bv;
            o.w = acc[mi][nj][3] + bv;
            *(float4*)&op[pxoff] = o;
        }
    }
}

// ---------------------------------------------------------------------------
extern "C" void kernel_launch(void* const* d_in, const int* in_sizes, int n_in,
                              void* d_out, int out_size, void* d_ws, size_t ws_size,
                              hipStream_t stream)
{
    const float* x  = (const float*)d_in[0];
    const float* ow = (const float*)d_in[1];
    const float* ob = (const float*)d_in[2];
    const float* dw = (const float*)d_in[3];
    const float* db = (const float*)d_in[4];
    float* out = (float*)d_out;

    // ws layout (bytes):
    // opart f32 [2][4][18][4096] = 2359296 | bp f16 1179648 | bow f16 147456 | xT f16 8388608
    char* wsp = (char*)d_ws;
    float*     opart = (float*)wsp;
    _Float16*  bp    = (_Float16*)(wsp + 2359296);
    _Float16*  bow   = (_Float16*)(wsp + 3538944);
    _Float16*  xT    = (_Float16*)(wsp + 3686400);

    hipLaunchKernelGGL(prework_kernel,     dim3(1348), dim3(256), 0, stream, x, ow, dw, xT, bp, bow);
    hipLaunchKernelGGL(offset_mfma_kernel, dim3(512),  dim3(256), 0, stream, xT, bow, opart);
    hipLaunchKernelGGL(dcn_mfma_kernel,    dim3(512),  dim3(512), 0, stream, xT, opart, ob, bp, db, out);
}